// Round 3
// baseline (467.536 us; speedup 1.0000x reference)
//
#include <hip/hip_runtime.h>

typedef unsigned short u16;
typedef unsigned int u32;
typedef short bf16x8 __attribute__((ext_vector_type(8)));
typedef float f32x4 __attribute__((ext_vector_type(4)));

#define DEV static __device__ __forceinline__

constexpr int CH = 16;          // n-chunks per batch for attention
constexpr int NB = 4096 / CH;   // 256 rows per chunk
constexpr float LN_EPS = 1e-5f;
constexpr float SCALE = 0.0625f; // 256^-0.5

DEV float bf2f(u32 u) { return __uint_as_float(u << 16); }
DEV float bfe(short x) { return __uint_as_float(((u32)(u16)x) << 16); }
DEV u16 f2bf(float f) {
  u32 u = __float_as_uint(f);
  return (u16)((u + 0x7fffu + ((u >> 16) & 1u)) >> 16);
}
DEV u32 pk2(float a, float b) { return (u32)f2bf(a) | ((u32)f2bf(b) << 16); }

// ---------------- K0: convert weights to bf16 ----------------
// wkvT[n][k]  (512x256)  B for the k/v GEMM (row-major n, k)
// MFMA-fragment-packed sets (16x16x32 tiles, frag idx = ((nt*KT+kt)*64+lane)*8+j,
//   element = W[kt*32+(lane>>4)*8+j][nt*16+(lane&15)]):
// wih_f: W_ih 256x768 (NT=48,KT=8)   whh_f: W_hh (NT=48,KT=8)
// w1_f:  W1 256x512  (NT=32,KT=8)    w2_f: W2 512x256 (NT=16,KT=16)
// wq_f:  Wq 256x256  (NT=16,KT=8)
// wqt[t][d] (256x256) per-thread stream for k_slots_init
__global__ __launch_bounds__(256) void k_convert(
    const float* __restrict__ Wk, const float* __restrict__ Wv,
    const float* __restrict__ Wih, const float* __restrict__ Whh,
    const float* __restrict__ W1, const float* __restrict__ W2,
    const float* __restrict__ Wq,
    u16* __restrict__ wkvT, u16* __restrict__ wih_f, u16* __restrict__ whh_f,
    u16* __restrict__ w1_f, u16* __restrict__ w2_f, u16* __restrict__ wq_f,
    u16* __restrict__ wqt) {
  int idx = blockIdx.x * 256 + threadIdx.x;
  if (idx < 131072) {                       // wkvT[n][k] = W(k,n)
    int n = idx >> 8, k = idx & 255;
    float v = (n < 256) ? Wk[k * 256 + n] : Wv[k * 256 + (n - 256)];
    wkvT[idx] = f2bf(v);
    return;
  }
  idx -= 131072;
  if (idx < 196608) {                       // wih_f
    int j = idx & 7, lane = (idx >> 3) & 63, tile = idx >> 9;
    int kt = tile & 7, nt = tile >> 3;
    int k = kt * 32 + ((lane >> 4) << 3) + j, n = nt * 16 + (lane & 15);
    wih_f[idx] = f2bf(Wih[k * 768 + n]);
    return;
  }
  idx -= 196608;
  if (idx < 196608) {                       // whh_f
    int j = idx & 7, lane = (idx >> 3) & 63, tile = idx >> 9;
    int kt = tile & 7, nt = tile >> 3;
    int k = kt * 32 + ((lane >> 4) << 3) + j, n = nt * 16 + (lane & 15);
    whh_f[idx] = f2bf(Whh[k * 768 + n]);
    return;
  }
  idx -= 196608;
  if (idx < 131072) {                       // w1_f
    int j = idx & 7, lane = (idx >> 3) & 63, tile = idx >> 9;
    int kt = tile & 7, nt = tile >> 3;
    int k = kt * 32 + ((lane >> 4) << 3) + j, n = nt * 16 + (lane & 15);
    w1_f[idx] = f2bf(W1[k * 512 + n]);
    return;
  }
  idx -= 131072;
  if (idx < 131072) {                       // w2_f (KT=16)
    int j = idx & 7, lane = (idx >> 3) & 63, tile = idx >> 9;
    int kt = tile & 15, nt = tile >> 4;
    int k = kt * 32 + ((lane >> 4) << 3) + j, n = nt * 16 + (lane & 15);
    w2_f[idx] = f2bf(W2[k * 256 + n]);
    return;
  }
  idx -= 131072;
  if (idx < 65536) {                        // wq_f
    int j = idx & 7, lane = (idx >> 3) & 63, tile = idx >> 9;
    int kt = tile & 7, nt = tile >> 3;
    int k = kt * 32 + ((lane >> 4) << 3) + j, n = nt * 16 + (lane & 15);
    wq_f[idx] = f2bf(Wq[k * 256 + n]);
    return;
  }
  idx -= 65536;
  if (idx < 65536) {                        // wqt[t][d] = Wq[d][t]
    int t = idx >> 8, d = idx & 255;
    wqt[idx] = f2bf(Wq[d * 256 + t]);
    return;
  }
}

// ---------------- K1: LayerNorm(inputs) -> x bf16 ----------------
__global__ __launch_bounds__(256) void k_ln(const float* __restrict__ in,
    const float* __restrict__ g, const float* __restrict__ b,
    u16* __restrict__ xbf) {
  int row = blockIdx.x * 4 + (threadIdx.x >> 6);
  int lane = threadIdx.x & 63;
  float4 v = ((const float4*)(in + (size_t)row * 256))[lane];
  float s = v.x + v.y + v.z + v.w;
  float ss = v.x * v.x + v.y * v.y + v.z * v.z + v.w * v.w;
#pragma unroll
  for (int o = 32; o; o >>= 1) { s += __shfl_xor(s, o); ss += __shfl_xor(ss, o); }
  float mean = s * (1.f / 256.f);
  float rstd = rsqrtf(ss * (1.f / 256.f) - mean * mean + LN_EPS);
  float4 gv = ((const float4*)g)[lane];
  float4 bv = ((const float4*)b)[lane];
  uint2 o;
  o.x = pk2((v.x - mean) * rstd * gv.x + bv.x, (v.y - mean) * rstd * gv.y + bv.y);
  o.y = pk2((v.z - mean) * rstd * gv.z + bv.z, (v.w - mean) * rstd * gv.w + bv.w);
  ((uint2*)(xbf + (size_t)row * 256))[lane] = o;
}

// ---------------- K2: slots init + first q ----------------
__global__ __launch_bounds__(256) void k_slots_init(
    const float* __restrict__ noise, const float* __restrict__ mu,
    const float* __restrict__ sig, const float* __restrict__ g,
    const float* __restrict__ b, const u16* __restrict__ wqt,
    float* __restrict__ slots, float* __restrict__ qbuf) {
  int bs = blockIdx.x, t = threadIdx.x;
  float sg = sig[t];
  float sp = (sg > 20.f) ? sg : log1pf(expf(sg));
  sp = fminf(fmaxf(sp, 0.1f), 2.0f);
  float sl = mu[t] + sp * noise[bs * 256 + t];
  slots[bs * 256 + t] = sl;
  __shared__ float red[8];
  __shared__ __align__(16) float sln[256];
  float s = sl, ss = sl * sl;
#pragma unroll
  for (int o = 32; o; o >>= 1) { s += __shfl_xor(s, o); ss += __shfl_xor(ss, o); }
  int w = t >> 6;
  if ((t & 63) == 0) { red[w] = s; red[4 + w] = ss; }
  __syncthreads();
  s = red[0] + red[1] + red[2] + red[3];
  ss = red[4] + red[5] + red[6] + red[7];
  float mean = s * (1.f / 256.f);
  float rstd = rsqrtf(ss * (1.f / 256.f) - mean * mean + LN_EPS);
  sln[t] = (sl - mean) * rstd * g[t] + b[t];
  __syncthreads();
  float acc = 0.f;
  const bf16x8* wqp = (const bf16x8*)(wqt + t * 256);
#pragma unroll 4
  for (int db = 0; db < 32; ++db) {
    float q8[8];
    *(float4*)q8 = *(const float4*)&sln[db * 8];
    *(float4*)(q8 + 4) = *(const float4*)&sln[db * 8 + 4];
    bf16x8 wv = wqp[db];
#pragma unroll
    for (int j = 0; j < 8; ++j) acc += q8[j] * bfe(wv[j]);
  }
  qbuf[bs * 256 + t] = acc;
}

// ---------------- KG: kv = x @ [Wk|Wv] (bf16 MFMA), k written transposed ----------------
__global__ __launch_bounds__(256) void k_gemm(
    const u16* __restrict__ X, const u16* __restrict__ Wt,
    u16* __restrict__ kT, u16* __restrict__ Vv) {
  __shared__ u16 smem[16896];   // A[0..8191], B[8192..16383] staging; bounce 128x132
  int bid = blockIdx.x;
  int mt = bid >> 2, nt = bid & 3;
  int w = threadIdx.x >> 6, lane = threadIdx.x & 63;
  int wr = w >> 1, wc = w & 1;
  f32x4 acc[4][4] = {};
  for (int ks = 0; ks < 4; ++ks) {
#pragma unroll
    for (int i = 0; i < 4; ++i) {
      int cbase = (w * 4 + i) * 64;
      int c = cbase + lane;
      int r = c >> 3;
      int swz = (c & 7) ^ (r & 7);
      const u16* srcA = X + (mt * 128 + r) * 256 + ks * 64 + swz * 8;
      const u16* srcB = Wt + (nt * 128 + r) * 256 + ks * 64 + swz * 8;
      __builtin_amdgcn_global_load_lds(
          (const __attribute__((address_space(1))) void*)srcA,
          (__attribute__((address_space(3))) void*)(smem + cbase * 8), 16, 0, 0);
      __builtin_amdgcn_global_load_lds(
          (const __attribute__((address_space(1))) void*)srcB,
          (__attribute__((address_space(3))) void*)(smem + 8192 + cbase * 8), 16, 0, 0);
    }
    __syncthreads();
#pragma unroll
    for (int kk = 0; kk < 2; ++kk) {
      bf16x8 af[4], bfr[4];
#pragma unroll
      for (int m = 0; m < 4; ++m) {
        int lrow = wr * 64 + m * 16 + (lane & 15);
        int slot = (kk * 4 + (lane >> 4)) ^ (lrow & 7);
        af[m] = *(const bf16x8*)((const char*)smem + lrow * 128 + slot * 16);
      }
#pragma unroll
      for (int n = 0; n < 4; ++n) {
        int lcol = wc * 64 + n * 16 + (lane & 15);
        int slot = (kk * 4 + (lane >> 4)) ^ (lcol & 7);
        bfr[n] = *(const bf16x8*)((const char*)smem + 16384 + lcol * 128 + slot * 16);
      }
#pragma unroll
      for (int m = 0; m < 4; ++m)
#pragma unroll
        for (int n = 0; n < 4; ++n)
          acc[m][n] = __builtin_amdgcn_mfma_f32_16x16x32_bf16(af[m], bfr[n], acc[m][n], 0, 0, 0);
    }
    __syncthreads();
  }
  int bb = (mt * 128) >> 12;
  int nb0 = (mt * 128) & 4095;
  if (nt < 2) {  // k output: transpose via LDS bounce -> kT[b][d][n]
#pragma unroll
    for (int m = 0; m < 4; ++m)
#pragma unroll
      for (int n = 0; n < 4; ++n) {
        int col = wc * 64 + n * 16 + (lane & 15);
        int r0 = wr * 64 + m * 16 + (lane >> 4) * 4;
        uint2 pk;
        pk.x = pk2(acc[m][n][0], acc[m][n][1]);
        pk.y = pk2(acc[m][n][2], acc[m][n][3]);
        *(uint2*)((char*)smem + col * 264 + r0 * 2) = pk;
      }
    __syncthreads();
    u16* outp = kT + bb * (1 << 20) + nt * 128 * 4096 + nb0;
    for (int i = 0; i < 32; ++i) {
      int dl = w * 32 + i;
      u32 val = *(const u32*)((const char*)smem + dl * 264 + lane * 4);
      *(u32*)(outp + dl * 4096 + 2 * lane) = val;
    }
  } else {       // v output: straight bounce -> Vv[b*4096+n][d]
#pragma unroll
    for (int m = 0; m < 4; ++m)
#pragma unroll
      for (int n = 0; n < 4; ++n) {
        int col = wc * 64 + n * 16 + (lane & 15);
        int r0 = wr * 64 + m * 16 + (lane >> 4) * 4;
#pragma unroll
        for (int j = 0; j < 4; ++j)
          *((u16*)((char*)smem + (r0 + j) * 264 + col * 2)) = f2bf(acc[m][n][j]);
      }
    __syncthreads();
    u16* outp = Vv + (mt * 128) * 256 + (nt - 2) * 128;
    for (int i = 0; i < 32; ++i) {
      int nl = w * 32 + i;
      u32 val = *(const u32*)((const char*)smem + nl * 264 + lane * 4);
      *(u32*)(outp + nl * 256 + 2 * lane) = val;
    }
  }
}

// ---------------- K3: attention partials (flash-style over n-chunks) ----------------
__global__ __launch_bounds__(128) void k_attn(
    const u16* __restrict__ kT, const u16* __restrict__ Vv,
    const float* __restrict__ qbuf,
    float* __restrict__ part_ml, float* __restrict__ part_upd) {
  int b = blockIdx.x >> 4, c = blockIdx.x & 15;
  int n0 = c * NB;
  int t = threadIdx.x;
  int w = t >> 6, lane = t & 63;
  __shared__ __align__(16) float qT[256][8];
  __shared__ __align__(16) float pl[NB][8];
  __shared__ float red[16];
  for (int i = t; i < 2048; i += 128) {
    int s = i >> 8, d = i & 255;
    qT[d][s] = qbuf[(b * 8 + s) * 256 + d];
  }
  __syncthreads();
  // phase 1: dots[n,s] for n = n0+2t, n0+2t+1
  float acc[8][2] = {};
  const u16* kp = kT + b * (1 << 20) + n0 + 2 * t;
#pragma unroll 8
  for (int d = 0; d < 256; ++d) {
    u32 kk = *(const u32*)(kp + d * 4096);
    float k0 = bf2f(kk & 0xffffu), k1 = bf2f(kk >> 16);
    float q8[8];
    *(float4*)q8 = *(const float4*)&qT[d][0];
    *(float4*)(q8 + 4) = *(const float4*)&qT[d][4];
#pragma unroll
    for (int s = 0; s < 8; ++s) { acc[s][0] += k0 * q8[s]; acc[s][1] += k1 * q8[s]; }
  }
  float mx[8];
#pragma unroll
  for (int s = 0; s < 8; ++s) {
    acc[s][0] *= SCALE; acc[s][1] *= SCALE;
    float lm = fmaxf(acc[s][0], acc[s][1]);
#pragma unroll
    for (int o = 32; o; o >>= 1) lm = fmaxf(lm, __shfl_xor(lm, o));
    if (lane == 0) red[w * 8 + s] = lm;
  }
  __syncthreads();
#pragma unroll
  for (int s = 0; s < 8; ++s) mx[s] = fmaxf(red[s], red[8 + s]);
  __syncthreads();
#pragma unroll
  for (int s = 0; s < 8; ++s) {
    float p0 = __expf(acc[s][0] - mx[s]);
    float p1 = __expf(acc[s][1] - mx[s]);
    pl[2 * t][s] = p0; pl[2 * t + 1][s] = p1;
    float l = p0 + p1;
#pragma unroll
    for (int o = 32; o; o >>= 1) l += __shfl_xor(l, o);
    if (lane == 0) red[w * 8 + s] = l;
  }
  __syncthreads();
  if (t < 8) {
    part_ml[(b * 16 + c) * 16 + t] = mx[t];
    part_ml[(b * 16 + c) * 16 + 8 + t] = red[t] + red[8 + t];
  }
  // phase 2: upd[s][d] partial, this thread owns d = 2t, 2t+1
  float upd[8][2] = {};
  const u16* vp = Vv + (b * 4096 + n0) * 256 + 2 * t;
#pragma unroll 4
  for (int n = 0; n < NB; ++n) {
    u32 vv = *(const u32*)(vp + n * 256);
    float v0 = bf2f(vv & 0xffffu), v1 = bf2f(vv >> 16);
    float p8[8];
    *(float4*)p8 = *(const float4*)&pl[n][0];
    *(float4*)(p8 + 4) = *(const float4*)&pl[n][4];
#pragma unroll
    for (int s = 0; s < 8; ++s) { upd[s][0] += p8[s] * v0; upd[s][1] += p8[s] * v1; }
  }
  float* up = part_upd + ((b * 16 + c) * 8) * 256 + 2 * t;
#pragma unroll
  for (int s = 0; s < 8; ++s) {
    float2 o2; o2.x = upd[s][0]; o2.y = upd[s][1];
    *(float2*)(up + s * 256) = o2;
  }
}

// ---------------- K4: per-batch MFMA update: combine + GRU + MLP + next q ----------------
__global__ __launch_bounds__(256) void k_update2(
    const float* __restrict__ pml, const float* __restrict__ pupd,
    const float* __restrict__ slots_in,
    const u16* __restrict__ wih_f, const u16* __restrict__ whh_f,
    const u16* __restrict__ w1_f, const u16* __restrict__ w2_f,
    const u16* __restrict__ wq_f,
    const float* __restrict__ bih, const float* __restrict__ bhh,
    const float* __restrict__ b1v, const float* __restrict__ b2v,
    const float* __restrict__ gm, const float* __restrict__ bm,
    const float* __restrict__ gs, const float* __restrict__ bsv,
    float* __restrict__ slots_out, float* __restrict__ qbuf, int write_q) {
  int b = blockIdx.x;
  int t = threadIdx.x, w = t >> 6, lane = t & 63;
  __shared__ float wc_l[16][8];
  __shared__ float redb[64];
  __shared__ __align__(16) u16 ubf[16 * 256];   // also reused as mbf / slbf
  __shared__ __align__(16) u16 hbf[16 * 256];
  __shared__ __align__(16) u16 h1bf[16 * 512];
  __shared__ __align__(16) float gxl[768 * 8];  // [n][s]
  __shared__ __align__(16) float ghl[768 * 8];
  __shared__ __align__(16) float h_f32[8 * 256];
  __shared__ __align__(16) float snew_l[8 * 256];
  __shared__ __align__(16) float sout_l[8 * 256];

  // phase 1: per-slot softmax-combine weights
  if (t < 8) {
    int s = t;
    float mv[16], lv[16], M = -1e30f;
#pragma unroll
    for (int c = 0; c < 16; ++c) {
      mv[c] = pml[(b * 16 + c) * 16 + s];
      lv[c] = pml[(b * 16 + c) * 16 + 8 + s];
      M = fmaxf(M, mv[c]);
    }
    float L = 0.f;
    float wcv[16];
#pragma unroll
    for (int c = 0; c < 16; ++c) { wcv[c] = __expf(mv[c] - M); L += lv[c] * wcv[c]; }
    float inv = 1.f / L;
#pragma unroll
    for (int c = 0; c < 16; ++c) wc_l[c][s] = wcv[c] * inv;
  }
  __syncthreads();
  // phase 2: stage u, h as swizzled bf16 A-operands (rows 8..15 zero)
#pragma unroll
  for (int s = 0; s < 8; ++s) {
    float acc = 0.f;
#pragma unroll 4
    for (int c = 0; c < 16; ++c)
      acc += wc_l[c][s] * pupd[((b * 16 + c) * 8 + s) * 256 + t];
    int byte = (s * 512 + t * 2) ^ ((s & 7) << 4);
    *(u16*)((char*)ubf + byte) = f2bf(acc);
    float hv = slots_in[(b * 8 + s) * 256 + t];
    h_f32[s * 256 + t] = hv;
    *(u16*)((char*)hbf + byte) = f2bf(hv);
    int zbyte = ((s + 8) * 512 + t * 2) ^ ((s & 7) << 4);
    *(u16*)((char*)ubf + zbyte) = 0;
    *(u16*)((char*)hbf + zbyte) = 0;
  }
  __syncthreads();

  auto afrag = [&](const u16* base, int stride, int kt) -> bf16x8 {
    int row = lane & 15;
    int byte = (row * stride + (kt * 32 + ((lane >> 4) << 3)) * 2) ^ ((row & 7) << 4);
    return *(const bf16x8*)((const char*)base + byte);
  };

  // phase 3: gate GEMMs  gx = u@W_ih, gh = h@W_hh  (96 16x16 tiles)
  for (int tl = w; tl < 96; tl += 4) {
    bool ih = tl < 48;
    int nt = ih ? tl : tl - 48;
    const bf16x8* bw = (const bf16x8*)(ih ? wih_f : whh_f);
    const u16* ab = ih ? ubf : hbf;
    f32x4 acc = {};
#pragma unroll
    for (int kt = 0; kt < 8; ++kt)
      acc = __builtin_amdgcn_mfma_f32_16x16x32_bf16(afrag(ab, 512, kt),
              bw[(nt * 8 + kt) * 64 + lane], acc, 0, 0, 0);
    int r0 = (lane >> 4) * 4;
    if (r0 < 8) {
      float* g = ih ? gxl : ghl;
      *(float4*)&g[(nt * 16 + (lane & 15)) * 8 + r0] = *(float4*)&acc;
    }
  }
  __syncthreads();

  // phase 4: GRU elementwise + LN(mlp) -> mbf (into ubf)
  float sn[8];
  {
    const float* pxr = gxl + t * 8;
    const float* pxz = gxl + (256 + t) * 8;
    const float* pxn = gxl + (512 + t) * 8;
    const float* phr = ghl + t * 8;
    const float* phz = ghl + (256 + t) * 8;
    const float* phn = ghl + (512 + t) * 8;
    float br = bih[t], bz = bih[256 + t], bn = bih[512 + t];
    float cr = bhh[t], cz = bhh[256 + t], cn = bhh[512 + t];
#pragma unroll
    for (int s = 0; s < 8; ++s) {
      float r = 1.f / (1.f + __expf(-(pxr[s] + br + phr[s] + cr)));
      float z = 1.f / (1.f + __expf(-(pxz[s] + bz + phz[s] + cz)));
      float ng = tanhf(pxn[s] + bn + r * (phn[s] + cn));
      sn[s] = (1.f - z) * ng + z * h_f32[s * 256 + t];
      snew_l[s * 256 + t] = sn[s];
    }
  }
#pragma unroll
  for (int s = 0; s < 8; ++s) {
    float a = sn[s], q = a * a;
#pragma unroll
    for (int o = 32; o; o >>= 1) { a += __shfl_xor(a, o); q += __shfl_xor(q, o); }
    if (lane == 0) { redb[w * 16 + s] = a; redb[w * 16 + 8 + s] = q; }
  }
  __syncthreads();
  {
    float gmt = gm[t], bmt = bm[t];
#pragma unroll
    for (int s = 0; s < 8; ++s) {
      float a = redb[s] + redb[16 + s] + redb[32 + s] + redb[48 + s];
      float q = redb[8 + s] + redb[24 + s] + redb[40 + s] + redb[56 + s];
      float mean = a * (1.f / 256.f);
      float rstd = rsqrtf(q * (1.f / 256.f) - mean * mean + LN_EPS);
      float mval = (sn[s] - mean) * rstd * gmt + bmt;
      int byte = (s * 512 + t * 2) ^ ((s & 7) << 4);
      *(u16*)((char*)ubf + byte) = f2bf(mval);
    }
  }
  __syncthreads();

  // phase 5: MLP1 (m @ W1 + b1, relu) -> h1bf (32 tiles)
  for (int tl = w; tl < 32; tl += 4) {
    const bf16x8* bw = (const bf16x8*)w1_f;
    f32x4 acc = {};
#pragma unroll
    for (int kt = 0; kt < 8; ++kt)
      acc = __builtin_amdgcn_mfma_f32_16x16x32_bf16(afrag(ubf, 512, kt),
              bw[(tl * 8 + kt) * 64 + lane], acc, 0, 0, 0);
    int col = tl * 16 + (lane & 15);
    int r0 = (lane >> 4) * 4;
    float bb = b1v[col];
#pragma unroll
    for (int j = 0; j < 4; ++j) {
      float vv = fmaxf(acc[j] + bb, 0.f);
      int byte = ((r0 + j) * 1024 + col * 2) ^ (((r0 + j) & 7) << 4);
      *(u16*)((char*)h1bf + byte) = f2bf(vv);
    }
  }
  __syncthreads();

  // phase 6: MLP2 (h1 @ W2 + b2) + residual -> sout (16 tiles, KT=16)
  for (int tl = w; tl < 16; tl += 4) {
    const bf16x8* bw = (const bf16x8*)w2_f;
    f32x4 acc = {};
#pragma unroll
    for (int kt = 0; kt < 16; ++kt)
      acc = __builtin_amdgcn_mfma_f32_16x16x32_bf16(afrag(h1bf, 1024, kt),
              bw[(tl * 16 + kt) * 64 + lane], acc, 0, 0, 0);
    int col = tl * 16 + (lane & 15);
    int r0 = (lane >> 4) * 4;
    if (r0 < 8) {
      float bb = b2v[col];
#pragma unroll
      for (int j = 0; j < 4; ++j) {
        int row = r0 + j;
        float so = acc[j] + bb + snew_l[row * 256 + col];
        sout_l[row * 256 + col] = so;
        slots_out[(b * 8 + row) * 256 + col] = so;
      }
    }
  }
  __syncthreads();

  // phase 7: LN(slot) + q GEMM for next iteration
  if (write_q) {
    float so8[8];
#pragma unroll
    for (int s = 0; s < 8; ++s) so8[s] = sout_l[s * 256 + t];
#pragma unroll
    for (int s = 0; s < 8; ++s) {
      float a = so8[s], q = a * a;
#pragma unroll
      for (int o = 32; o; o >>= 1) { a += __shfl_xor(a, o); q += __shfl_xor(q, o); }
      if (lane == 0) { redb[w * 16 + s] = a; redb[w * 16 + 8 + s] = q; }
    }
    __syncthreads();
    {
      float gst = gs[t], bst = bsv[t];
#pragma unroll
      for (int s = 0; s < 8; ++s) {
        float a = redb[s] + redb[16 + s] + redb[32 + s] + redb[48 + s];
        float q = redb[8 + s] + redb[24 + s] + redb[40 + s] + redb[56 + s];
        float mean = a * (1.f / 256.f);
        float rstd = rsqrtf(q * (1.f / 256.f) - mean * mean + LN_EPS);
        float sl = (so8[s] - mean) * rstd * gst + bst;
        int byte = (s * 512 + t * 2) ^ ((s & 7) << 4);
        *(u16*)((char*)ubf + byte) = f2bf(sl);
      }
    }
    __syncthreads();
    for (int tl = w; tl < 16; tl += 4) {
      const bf16x8* bw = (const bf16x8*)wq_f;
      f32x4 acc = {};
#pragma unroll
      for (int kt = 0; kt < 8; ++kt)
        acc = __builtin_amdgcn_mfma_f32_16x16x32_bf16(afrag(ubf, 512, kt),
                bw[(tl * 8 + kt) * 64 + lane], acc, 0, 0, 0);
      int col = tl * 16 + (lane & 15);
      int r0 = (lane >> 4) * 4;
      if (r0 < 8) {
#pragma unroll
        for (int j = 0; j < 4; ++j)
          qbuf[(b * 8 + r0 + j) * 256 + col] = acc[j];
      }
    }
  }
}

extern "C" void kernel_launch(void* const* d_in, const int* in_sizes, int n_in,
                              void* d_out, int out_size, void* d_ws, size_t ws_size,
                              hipStream_t stream) {
  (void)in_sizes; (void)n_in; (void)out_size; (void)ws_size;
  const float* inputs    = (const float*)d_in[0];
  const float* noise     = (const float*)d_in[1];
  const float* ln_in_g   = (const float*)d_in[2];
  const float* ln_in_b   = (const float*)d_in[3];
  const float* ln_slot_g = (const float*)d_in[4];
  const float* ln_slot_b = (const float*)d_in[5];
  const float* ln_mlp_g  = (const float*)d_in[6];
  const float* ln_mlp_b  = (const float*)d_in[7];
  const float* slot_mu   = (const float*)d_in[8];
  const float* slot_sig  = (const float*)d_in[9];
  const float* Wq        = (const float*)d_in[10];
  const float* Wk        = (const float*)d_in[11];
  const float* Wv        = (const float*)d_in[12];
  const float* W_ih      = (const float*)d_in[13];
  const float* W_hh      = (const float*)d_in[14];
  const float* b_ih      = (const float*)d_in[15];
  const float* b_hh      = (const float*)d_in[16];
  const float* W1        = (const float*)d_in[17];
  const float* b1        = (const float*)d_in[18];
  const float* W2        = (const float*)d_in[19];
  const float* b2        = (const float*)d_in[20];

  char* p = (char*)d_ws;
  auto take = [&](size_t bytes) { char* r = p; p += (bytes + 255) & ~(size_t)255; return r; };
  u16* xbf      = (u16*)take((size_t)131072 * 256 * 2);
  u16* kT       = (u16*)take((size_t)32 * 256 * 4096 * 2);
  u16* Vv       = (u16*)take((size_t)32 * 4096 * 256 * 2);
  u16* wkvT     = (u16*)take(131072 * 2);
  u16* wih_f    = (u16*)take(196608 * 2);
  u16* whh_f    = (u16*)take(196608 * 2);
  u16* w1_f     = (u16*)take(131072 * 2);
  u16* w2_f     = (u16*)take(131072 * 2);
  u16* wq_f     = (u16*)take(65536 * 2);
  u16* wqt      = (u16*)take(65536 * 2);
  float* slotsA = (float*)take(256 * 256 * 4);
  float* slotsB = (float*)take(256 * 256 * 4);
  float* qbuf   = (float*)take(256 * 256 * 4);
  float* pml    = (float*)take(32 * 16 * 16 * 4);
  float* pupd   = (float*)take((size_t)32 * 16 * 8 * 256 * 4);

  k_convert<<<3584, 256, 0, stream>>>(Wk, Wv, W_ih, W_hh, W1, W2, Wq,
                                      wkvT, wih_f, whh_f, w1_f, w2_f, wq_f, wqt);
  k_ln<<<32768, 256, 0, stream>>>(inputs, ln_in_g, ln_in_b, xbf);
  k_slots_init<<<256, 256, 0, stream>>>(noise, slot_mu, slot_sig, ln_slot_g, ln_slot_b, wqt, slotsA, qbuf);
  k_gemm<<<4096, 256, 0, stream>>>(xbf, wkvT, kT, Vv);

  const float* scur = slotsA;
  for (int it = 0; it < 3; ++it) {
    k_attn<<<512, 128, 0, stream>>>(kT, Vv, qbuf, pml, pupd);
    float* sout = (it == 2) ? (float*)d_out : ((it == 0) ? slotsB : slotsA);
    k_update2<<<32, 256, 0, stream>>>(pml, pupd, scur, wih_f, whh_f, w1_f, w2_f, wq_f,
        b_ih, b_hh, b1, b2, ln_mlp_g, ln_mlp_b, ln_slot_g, ln_slot_b,
        sout, qbuf, (it < 2) ? 1 : 0);
    scur = sout;
  }
}

// Round 4
// 324.675 us; speedup vs baseline: 1.4400x; 1.4400x over previous
//
#include <hip/hip_runtime.h>

typedef unsigned short u16;
typedef unsigned int u32;
typedef short bf16x8 __attribute__((ext_vector_type(8)));
typedef float f32x4 __attribute__((ext_vector_type(4)));

#define DEV static __device__ __forceinline__

constexpr int CH = 16;          // n-chunks per batch for attention
constexpr int NB = 4096 / CH;   // 256 rows per chunk
constexpr float LN_EPS = 1e-5f;
constexpr float SCALE = 0.0625f; // 256^-0.5

DEV float bf2f(u32 u) { return __uint_as_float(u << 16); }
DEV float bfe(short x) { return __uint_as_float(((u32)(u16)x) << 16); }
DEV u16 f2bf(float f) {
  u32 u = __float_as_uint(f);
  return (u16)((u + 0x7fffu + ((u >> 16) & 1u)) >> 16);
}
DEV u32 pk2(float a, float b) { return (u32)f2bf(a) | ((u32)f2bf(b) << 16); }

// A-fragment address for M=256 GEMMs: element (row, k), KT = K/32 tiles.
// idx = ((mt*KT + kt)*64 + lane)*8 + j ; lane = ((k>>3)&3)*16 + (row&15), j = k&7.

// ---------------- K0: convert weights to bf16 ----------------
__global__ __launch_bounds__(256) void k_convert(
    const float* __restrict__ Wk, const float* __restrict__ Wv,
    const float* __restrict__ Wih, const float* __restrict__ Whh,
    const float* __restrict__ W1, const float* __restrict__ W2,
    const float* __restrict__ Wq,
    u16* __restrict__ wkvT, u16* __restrict__ wih_f, u16* __restrict__ whh_f,
    u16* __restrict__ w1_f, u16* __restrict__ w2_f, u16* __restrict__ wq_f,
    u16* __restrict__ wqt) {
  int idx = blockIdx.x * 256 + threadIdx.x;
  if (idx < 131072) {                       // wkvT[n][k] = W(k,n)
    int n = idx >> 8, k = idx & 255;
    float v = (n < 256) ? Wk[k * 256 + n] : Wv[k * 256 + (n - 256)];
    wkvT[idx] = f2bf(v);
    return;
  }
  idx -= 131072;
  if (idx < 196608) {                       // wih_f
    int j = idx & 7, lane = (idx >> 3) & 63, tile = idx >> 9;
    int kt = tile & 7, nt = tile >> 3;
    int k = kt * 32 + ((lane >> 4) << 3) + j, n = nt * 16 + (lane & 15);
    wih_f[idx] = f2bf(Wih[k * 768 + n]);
    return;
  }
  idx -= 196608;
  if (idx < 196608) {                       // whh_f
    int j = idx & 7, lane = (idx >> 3) & 63, tile = idx >> 9;
    int kt = tile & 7, nt = tile >> 3;
    int k = kt * 32 + ((lane >> 4) << 3) + j, n = nt * 16 + (lane & 15);
    whh_f[idx] = f2bf(Whh[k * 768 + n]);
    return;
  }
  idx -= 196608;
  if (idx < 131072) {                       // w1_f
    int j = idx & 7, lane = (idx >> 3) & 63, tile = idx >> 9;
    int kt = tile & 7, nt = tile >> 3;
    int k = kt * 32 + ((lane >> 4) << 3) + j, n = nt * 16 + (lane & 15);
    w1_f[idx] = f2bf(W1[k * 512 + n]);
    return;
  }
  idx -= 131072;
  if (idx < 131072) {                       // w2_f (KT=16)
    int j = idx & 7, lane = (idx >> 3) & 63, tile = idx >> 9;
    int kt = tile & 15, nt = tile >> 4;
    int k = kt * 32 + ((lane >> 4) << 3) + j, n = nt * 16 + (lane & 15);
    w2_f[idx] = f2bf(W2[k * 256 + n]);
    return;
  }
  idx -= 131072;
  if (idx < 65536) {                        // wq_f
    int j = idx & 7, lane = (idx >> 3) & 63, tile = idx >> 9;
    int kt = tile & 7, nt = tile >> 3;
    int k = kt * 32 + ((lane >> 4) << 3) + j, n = nt * 16 + (lane & 15);
    wq_f[idx] = f2bf(Wq[k * 256 + n]);
    return;
  }
  idx -= 65536;
  if (idx < 65536) {                        // wqt[t][d] = Wq[d][t]
    int t = idx >> 8, d = idx & 255;
    wqt[idx] = f2bf(Wq[d * 256 + t]);
    return;
  }
}

// ---------------- K1: LayerNorm(inputs) -> x bf16 ----------------
__global__ __launch_bounds__(256) void k_ln(const float* __restrict__ in,
    const float* __restrict__ g, const float* __restrict__ b,
    u16* __restrict__ xbf) {
  int row = blockIdx.x * 4 + (threadIdx.x >> 6);
  int lane = threadIdx.x & 63;
  float4 v = ((const float4*)(in + (size_t)row * 256))[lane];
  float s = v.x + v.y + v.z + v.w;
  float ss = v.x * v.x + v.y * v.y + v.z * v.z + v.w * v.w;
#pragma unroll
  for (int o = 32; o; o >>= 1) { s += __shfl_xor(s, o); ss += __shfl_xor(ss, o); }
  float mean = s * (1.f / 256.f);
  float rstd = rsqrtf(ss * (1.f / 256.f) - mean * mean + LN_EPS);
  float4 gv = ((const float4*)g)[lane];
  float4 bv = ((const float4*)b)[lane];
  uint2 o;
  o.x = pk2((v.x - mean) * rstd * gv.x + bv.x, (v.y - mean) * rstd * gv.y + bv.y);
  o.y = pk2((v.z - mean) * rstd * gv.z + bv.z, (v.w - mean) * rstd * gv.w + bv.w);
  ((uint2*)(xbf + (size_t)row * 256))[lane] = o;
}

// ---------------- K2: slots init + first q ----------------
__global__ __launch_bounds__(256) void k_slots_init(
    const float* __restrict__ noise, const float* __restrict__ mu,
    const float* __restrict__ sig, const float* __restrict__ g,
    const float* __restrict__ b, const u16* __restrict__ wqt,
    float* __restrict__ slots, float* __restrict__ qbuf) {
  int bs = blockIdx.x, t = threadIdx.x;
  float sg = sig[t];
  float sp = (sg > 20.f) ? sg : log1pf(expf(sg));
  sp = fminf(fmaxf(sp, 0.1f), 2.0f);
  float sl = mu[t] + sp * noise[bs * 256 + t];
  slots[bs * 256 + t] = sl;
  __shared__ float red[8];
  __shared__ __align__(16) float sln[256];
  float s = sl, ss = sl * sl;
#pragma unroll
  for (int o = 32; o; o >>= 1) { s += __shfl_xor(s, o); ss += __shfl_xor(ss, o); }
  int w = t >> 6;
  if ((t & 63) == 0) { red[w] = s; red[4 + w] = ss; }
  __syncthreads();
  s = red[0] + red[1] + red[2] + red[3];
  ss = red[4] + red[5] + red[6] + red[7];
  float mean = s * (1.f / 256.f);
  float rstd = rsqrtf(ss * (1.f / 256.f) - mean * mean + LN_EPS);
  sln[t] = (sl - mean) * rstd * g[t] + b[t];
  __syncthreads();
  float acc = 0.f;
  const bf16x8* wqp = (const bf16x8*)(wqt + t * 256);
#pragma unroll 4
  for (int db = 0; db < 32; ++db) {
    float q8[8];
    *(float4*)q8 = *(const float4*)&sln[db * 8];
    *(float4*)(q8 + 4) = *(const float4*)&sln[db * 8 + 4];
    bf16x8 wv = wqp[db];
#pragma unroll
    for (int j = 0; j < 8; ++j) acc += q8[j] * bfe(wv[j]);
  }
  qbuf[bs * 256 + t] = acc;
}

// ---------------- KG: kv = x @ [Wk|Wv] (bf16 MFMA), k written transposed ----------------
__global__ __launch_bounds__(256) void k_gemm(
    const u16* __restrict__ X, const u16* __restrict__ Wt,
    u16* __restrict__ kT, u16* __restrict__ Vv) {
  __shared__ u16 smem[16896];
  int bid = blockIdx.x;
  int mt = bid >> 2, nt = bid & 3;
  int w = threadIdx.x >> 6, lane = threadIdx.x & 63;
  int wr = w >> 1, wc = w & 1;
  f32x4 acc[4][4] = {};
  for (int ks = 0; ks < 4; ++ks) {
#pragma unroll
    for (int i = 0; i < 4; ++i) {
      int cbase = (w * 4 + i) * 64;
      int c = cbase + lane;
      int r = c >> 3;
      int swz = (c & 7) ^ (r & 7);
      const u16* srcA = X + (mt * 128 + r) * 256 + ks * 64 + swz * 8;
      const u16* srcB = Wt + (nt * 128 + r) * 256 + ks * 64 + swz * 8;
      __builtin_amdgcn_global_load_lds(
          (const __attribute__((address_space(1))) void*)srcA,
          (__attribute__((address_space(3))) void*)(smem + cbase * 8), 16, 0, 0);
      __builtin_amdgcn_global_load_lds(
          (const __attribute__((address_space(1))) void*)srcB,
          (__attribute__((address_space(3))) void*)(smem + 8192 + cbase * 8), 16, 0, 0);
    }
    __syncthreads();
#pragma unroll
    for (int kk = 0; kk < 2; ++kk) {
      bf16x8 af[4], bfr[4];
#pragma unroll
      for (int m = 0; m < 4; ++m) {
        int lrow = wr * 64 + m * 16 + (lane & 15);
        int slot = (kk * 4 + (lane >> 4)) ^ (lrow & 7);
        af[m] = *(const bf16x8*)((const char*)smem + lrow * 128 + slot * 16);
      }
#pragma unroll
      for (int n = 0; n < 4; ++n) {
        int lcol = wc * 64 + n * 16 + (lane & 15);
        int slot = (kk * 4 + (lane >> 4)) ^ (lcol & 7);
        bfr[n] = *(const bf16x8*)((const char*)smem + 16384 + lcol * 128 + slot * 16);
      }
#pragma unroll
      for (int m = 0; m < 4; ++m)
#pragma unroll
        for (int n = 0; n < 4; ++n)
          acc[m][n] = __builtin_amdgcn_mfma_f32_16x16x32_bf16(af[m], bfr[n], acc[m][n], 0, 0, 0);
    }
    __syncthreads();
  }
  int bb = (mt * 128) >> 12;
  int nb0 = (mt * 128) & 4095;
  if (nt < 2) {  // k output: transpose via LDS bounce -> kT[b][d][n]
#pragma unroll
    for (int m = 0; m < 4; ++m)
#pragma unroll
      for (int n = 0; n < 4; ++n) {
        int col = wc * 64 + n * 16 + (lane & 15);
        int r0 = wr * 64 + m * 16 + (lane >> 4) * 4;
        uint2 pk;
        pk.x = pk2(acc[m][n][0], acc[m][n][1]);
        pk.y = pk2(acc[m][n][2], acc[m][n][3]);
        *(uint2*)((char*)smem + col * 264 + r0 * 2) = pk;
      }
    __syncthreads();
    u16* outp = kT + bb * (1 << 20) + nt * 128 * 4096 + nb0;
    for (int i = 0; i < 32; ++i) {
      int dl = w * 32 + i;
      u32 val = *(const u32*)((const char*)smem + dl * 264 + lane * 4);
      *(u32*)(outp + dl * 4096 + 2 * lane) = val;
    }
  } else {       // v output: straight bounce -> Vv[b*4096+n][d]
#pragma unroll
    for (int m = 0; m < 4; ++m)
#pragma unroll
      for (int n = 0; n < 4; ++n) {
        int col = wc * 64 + n * 16 + (lane & 15);
        int r0 = wr * 64 + m * 16 + (lane >> 4) * 4;
#pragma unroll
        for (int j = 0; j < 4; ++j)
          *((u16*)((char*)smem + (r0 + j) * 264 + col * 2)) = f2bf(acc[m][n][j]);
      }
    __syncthreads();
    u16* outp = Vv + (mt * 128) * 256 + (nt - 2) * 128;
    for (int i = 0; i < 32; ++i) {
      int nl = w * 32 + i;
      u32 val = *(const u32*)((const char*)smem + nl * 264 + lane * 4);
      *(u32*)(outp + nl * 256 + 2 * lane) = val;
    }
  }
}

// ---------------- K3: attention partials (flash-style over n-chunks) ----------------
__global__ __launch_bounds__(128) void k_attn(
    const u16* __restrict__ kT, const u16* __restrict__ Vv,
    const float* __restrict__ qbuf,
    float* __restrict__ part_ml, float* __restrict__ part_upd) {
  int b = blockIdx.x >> 4, c = blockIdx.x & 15;
  int n0 = c * NB;
  int t = threadIdx.x;
  int w = t >> 6, lane = t & 63;
  __shared__ __align__(16) float qT[256][8];
  __shared__ __align__(16) float pl[NB][8];
  __shared__ float red[16];
  for (int i = t; i < 2048; i += 128) {
    int s = i >> 8, d = i & 255;
    qT[d][s] = qbuf[(b * 8 + s) * 256 + d];
  }
  __syncthreads();
  float acc[8][2] = {};
  const u16* kp = kT + b * (1 << 20) + n0 + 2 * t;
#pragma unroll 8
  for (int d = 0; d < 256; ++d) {
    u32 kk = *(const u32*)(kp + d * 4096);
    float k0 = bf2f(kk & 0xffffu), k1 = bf2f(kk >> 16);
    float q8[8];
    *(float4*)q8 = *(const float4*)&qT[d][0];
    *(float4*)(q8 + 4) = *(const float4*)&qT[d][4];
#pragma unroll
    for (int s = 0; s < 8; ++s) { acc[s][0] += k0 * q8[s]; acc[s][1] += k1 * q8[s]; }
  }
  float mx[8];
#pragma unroll
  for (int s = 0; s < 8; ++s) {
    acc[s][0] *= SCALE; acc[s][1] *= SCALE;
    float lm = fmaxf(acc[s][0], acc[s][1]);
#pragma unroll
    for (int o = 32; o; o >>= 1) lm = fmaxf(lm, __shfl_xor(lm, o));
    if (lane == 0) red[w * 8 + s] = lm;
  }
  __syncthreads();
#pragma unroll
  for (int s = 0; s < 8; ++s) mx[s] = fmaxf(red[s], red[8 + s]);
  __syncthreads();
#pragma unroll
  for (int s = 0; s < 8; ++s) {
    float p0 = __expf(acc[s][0] - mx[s]);
    float p1 = __expf(acc[s][1] - mx[s]);
    pl[2 * t][s] = p0; pl[2 * t + 1][s] = p1;
    float l = p0 + p1;
#pragma unroll
    for (int o = 32; o; o >>= 1) l += __shfl_xor(l, o);
    if (lane == 0) red[w * 8 + s] = l;
  }
  __syncthreads();
  if (t < 8) {
    part_ml[(b * 16 + c) * 16 + t] = mx[t];
    part_ml[(b * 16 + c) * 16 + 8 + t] = red[t] + red[8 + t];
  }
  float upd[8][2] = {};
  const u16* vp = Vv + (b * 4096 + n0) * 256 + 2 * t;
#pragma unroll 4
  for (int n = 0; n < NB; ++n) {
    u32 vv = *(const u32*)(vp + n * 256);
    float v0 = bf2f(vv & 0xffffu), v1 = bf2f(vv >> 16);
    float p8[8];
    *(float4*)p8 = *(const float4*)&pl[n][0];
    *(float4*)(p8 + 4) = *(const float4*)&pl[n][4];
#pragma unroll
    for (int s = 0; s < 8; ++s) { upd[s][0] += p8[s] * v0; upd[s][1] += p8[s] * v1; }
  }
  float* up = part_upd + ((b * 16 + c) * 8) * 256 + 2 * t;
#pragma unroll
  for (int s = 0; s < 8; ++s) {
    float2 o2; o2.x = upd[s][0]; o2.y = upd[s][1];
    *(float2*)(up + s * 256) = o2;
  }
}

// ---------------- U1: combine partials -> u frag; stage h frag ----------------
__global__ __launch_bounds__(256) void k_comb(
    const float* __restrict__ pml, const float* __restrict__ pupd,
    const float* __restrict__ slots_in,
    u16* __restrict__ ufrag, u16* __restrict__ hfrag) {
  int w = threadIdx.x >> 6, lane = threadIdx.x & 63;
  int row = blockIdx.x * 4 + w;
  int b = row >> 3, s = row & 7;
  float mv[16], lv[16], M = -1e30f;
#pragma unroll
  for (int c = 0; c < 16; ++c) {
    mv[c] = pml[(b * 16 + c) * 16 + s];
    lv[c] = pml[(b * 16 + c) * 16 + 8 + s];
    M = fmaxf(M, mv[c]);
  }
  float L = 0.f;
#pragma unroll
  for (int c = 0; c < 16; ++c) { mv[c] = __expf(mv[c] - M); L += lv[c] * mv[c]; }
  float inv = 1.f / L;
  int d0 = lane * 4;
  float4 acc = {0.f, 0.f, 0.f, 0.f};
#pragma unroll
  for (int c = 0; c < 16; ++c) {
    float4 p = *(const float4*)(pupd + (size_t)((b * 16 + c) * 8 + s) * 256 + d0);
    float wc = mv[c] * inv;
    acc.x += wc * p.x; acc.y += wc * p.y; acc.z += wc * p.z; acc.w += wc * p.w;
  }
  int mt = row >> 4, kt = d0 >> 5;
  int laneA = ((d0 >> 3) & 3) * 16 + (row & 15);
  int j0 = d0 & 7;
  uint2 pk;
  pk.x = pk2(acc.x, acc.y); pk.y = pk2(acc.z, acc.w);
  *(uint2*)(ufrag + ((mt * 8 + kt) * 64 + laneA) * 8 + j0) = pk;
  float4 hv = *(const float4*)(slots_in + row * 256 + d0);
  pk.x = pk2(hv.x, hv.y); pk.y = pk2(hv.z, hv.w);
  *(uint2*)(hfrag + ((mt * 8 + kt) * 64 + laneA) * 8 + j0) = pk;
}

// ---------------- U2: gates GEMM + GRU elementwise -> snew ----------------
__global__ __launch_bounds__(256) void k_gru(
    const u16* __restrict__ ufrag, const u16* __restrict__ hfrag,
    const u16* __restrict__ wih_f, const u16* __restrict__ whh_f,
    const float* __restrict__ bih, const float* __restrict__ bhh,
    const float* __restrict__ slots_in, float* __restrict__ snew) {
  int w = threadIdx.x >> 6, lane = threadIdx.x & 63;
  int unit = blockIdx.x * 4 + w;
  int mt = unit >> 4, g = unit & 15;
  const bf16x8* wih = (const bf16x8*)wih_f;
  const bf16x8* whh = (const bf16x8*)whh_f;
  f32x4 ar = {}, az = {}, an = {}, hr = {}, hz = {}, hn = {};
#pragma unroll
  for (int kt = 0; kt < 8; ++kt) {
    bf16x8 au = *(const bf16x8*)(ufrag + ((mt * 8 + kt) * 64 + lane) * 8);
    bf16x8 ah = *(const bf16x8*)(hfrag + ((mt * 8 + kt) * 64 + lane) * 8);
    ar = __builtin_amdgcn_mfma_f32_16x16x32_bf16(au, wih[(g * 8 + kt) * 64 + lane], ar, 0, 0, 0);
    az = __builtin_amdgcn_mfma_f32_16x16x32_bf16(au, wih[((16 + g) * 8 + kt) * 64 + lane], az, 0, 0, 0);
    an = __builtin_amdgcn_mfma_f32_16x16x32_bf16(au, wih[((32 + g) * 8 + kt) * 64 + lane], an, 0, 0, 0);
    hr = __builtin_amdgcn_mfma_f32_16x16x32_bf16(ah, whh[(g * 8 + kt) * 64 + lane], hr, 0, 0, 0);
    hz = __builtin_amdgcn_mfma_f32_16x16x32_bf16(ah, whh[((16 + g) * 8 + kt) * 64 + lane], hz, 0, 0, 0);
    hn = __builtin_amdgcn_mfma_f32_16x16x32_bf16(ah, whh[((32 + g) * 8 + kt) * 64 + lane], hn, 0, 0, 0);
  }
  int t = g * 16 + (lane & 15);
  float cr = bih[t], cz = bih[256 + t], cn = bih[512 + t];
  float dr = bhh[t], dz = bhh[256 + t], dn = bhh[512 + t];
#pragma unroll
  for (int j = 0; j < 4; ++j) {
    int row = mt * 16 + (lane >> 4) * 4 + j;
    float r = 1.f / (1.f + __expf(-(ar[j] + cr + hr[j] + dr)));
    float z = 1.f / (1.f + __expf(-(az[j] + cz + hz[j] + dz)));
    float ng = tanhf(an[j] + cn + r * (hn[j] + dn));
    float h = slots_in[row * 256 + t];
    snew[row * 256 + t] = (1.f - z) * ng + z * h;
  }
}

// ---------------- U3: row-wise LayerNorm -> bf16 A-fragments ----------------
__global__ __launch_bounds__(256) void k_rowln(
    const float* __restrict__ xin, const float* __restrict__ g,
    const float* __restrict__ bb, u16* __restrict__ frag) {
  int w = threadIdx.x >> 6, lane = threadIdx.x & 63;
  int row = blockIdx.x * 4 + w;
  int d0 = lane * 4;
  float4 v = *(const float4*)(xin + row * 256 + d0);
  float s = v.x + v.y + v.z + v.w;
  float ss = v.x * v.x + v.y * v.y + v.z * v.z + v.w * v.w;
#pragma unroll
  for (int o = 32; o; o >>= 1) { s += __shfl_xor(s, o); ss += __shfl_xor(ss, o); }
  float mean = s * (1.f / 256.f);
  float rstd = rsqrtf(ss * (1.f / 256.f) - mean * mean + LN_EPS);
  float4 gv = *(const float4*)(g + d0);
  float4 bv = *(const float4*)(bb + d0);
  float o0 = (v.x - mean) * rstd * gv.x + bv.x;
  float o1 = (v.y - mean) * rstd * gv.y + bv.y;
  float o2 = (v.z - mean) * rstd * gv.z + bv.z;
  float o3 = (v.w - mean) * rstd * gv.w + bv.w;
  int mt = row >> 4, kt = d0 >> 5;
  int laneA = ((d0 >> 3) & 3) * 16 + (row & 15);
  int j0 = d0 & 7;
  uint2 pk;
  pk.x = pk2(o0, o1); pk.y = pk2(o2, o3);
  *(uint2*)(frag + ((mt * 8 + kt) * 64 + laneA) * 8 + j0) = pk;
}

// ---------------- U4: MLP1 (relu(m@W1+b1)) -> h1 frags (KT=16) ----------------
__global__ __launch_bounds__(256) void k_mlp1(
    const u16* __restrict__ mfrag, const u16* __restrict__ w1_f,
    const float* __restrict__ b1v, u16* __restrict__ h1frag) {
  int w = threadIdx.x >> 6, lane = threadIdx.x & 63;
  int unit = blockIdx.x * 4 + w;       // 0..511
  int mt = unit >> 5, nt = unit & 31;
  const bf16x8* bw = (const bf16x8*)w1_f;
  f32x4 acc = {};
#pragma unroll
  for (int kt = 0; kt < 8; ++kt)
    acc = __builtin_amdgcn_mfma_f32_16x16x32_bf16(
        *(const bf16x8*)(mfrag + ((mt * 8 + kt) * 64 + lane) * 8),
        bw[(nt * 8 + kt) * 64 + lane], acc, 0, 0, 0);
  int col = nt * 16 + (lane & 15);     // = k2 of the next GEMM
  float bbv = b1v[col];
  int kt2 = col >> 5;
  int j2 = col & 7;
  int laneBase = ((col >> 3) & 3) * 16;
#pragma unroll
  for (int j = 0; j < 4; ++j) {
    int row = mt * 16 + (lane >> 4) * 4 + j;
    float vv = fmaxf(acc[j] + bbv, 0.f);
    h1frag[((mt * 16 + kt2) * 64 + laneBase + (row & 15)) * 8 + j2] = f2bf(vv);
  }
}

// ---------------- U5: MLP2 (h1@W2+b2) + residual -> sout ----------------
__global__ __launch_bounds__(256) void k_mlp2(
    const u16* __restrict__ h1frag, const u16* __restrict__ w2_f,
    const float* __restrict__ b2v, const float* __restrict__ snew,
    float* __restrict__ sout) {
  int w = threadIdx.x >> 6, lane = threadIdx.x & 63;
  int unit = blockIdx.x * 4 + w;       // 0..255
  int mt = unit >> 4, nt = unit & 15;
  const bf16x8* bw = (const bf16x8*)w2_f;
  f32x4 acc = {};
#pragma unroll
  for (int kt = 0; kt < 16; ++kt)
    acc = __builtin_amdgcn_mfma_f32_16x16x32_bf16(
        *(const bf16x8*)(h1frag + ((mt * 16 + kt) * 64 + lane) * 8),
        bw[(nt * 16 + kt) * 64 + lane], acc, 0, 0, 0);
  int col = nt * 16 + (lane & 15);
  float bbv = b2v[col];
#pragma unroll
  for (int j = 0; j < 4; ++j) {
    int row = mt * 16 + (lane >> 4) * 4 + j;
    sout[row * 256 + col] = acc[j] + bbv + snew[row * 256 + col];
  }
}

// ---------------- U6: q = sl @ Wq ----------------
__global__ __launch_bounds__(256) void k_q(
    const u16* __restrict__ slfrag, const u16* __restrict__ wq_f,
    float* __restrict__ qbuf) {
  int w = threadIdx.x >> 6, lane = threadIdx.x & 63;
  int unit = blockIdx.x * 4 + w;       // 0..255
  int mt = unit >> 4, nt = unit & 15;
  const bf16x8* bw = (const bf16x8*)wq_f;
  f32x4 acc = {};
#pragma unroll
  for (int kt = 0; kt < 8; ++kt)
    acc = __builtin_amdgcn_mfma_f32_16x16x32_bf16(
        *(const bf16x8*)(slfrag + ((mt * 8 + kt) * 64 + lane) * 8),
        bw[(nt * 8 + kt) * 64 + lane], acc, 0, 0, 0);
  int col = nt * 16 + (lane & 15);
#pragma unroll
  for (int j = 0; j < 4; ++j) {
    int row = mt * 16 + (lane >> 4) * 4 + j;
    qbuf[row * 256 + col] = acc[j];
  }
}

extern "C" void kernel_launch(void* const* d_in, const int* in_sizes, int n_in,
                              void* d_out, int out_size, void* d_ws, size_t ws_size,
                              hipStream_t stream) {
  (void)in_sizes; (void)n_in; (void)out_size; (void)ws_size;
  const float* inputs    = (const float*)d_in[0];
  const float* noise     = (const float*)d_in[1];
  const float* ln_in_g   = (const float*)d_in[2];
  const float* ln_in_b   = (const float*)d_in[3];
  const float* ln_slot_g = (const float*)d_in[4];
  const float* ln_slot_b = (const float*)d_in[5];
  const float* ln_mlp_g  = (const float*)d_in[6];
  const float* ln_mlp_b  = (const float*)d_in[7];
  const float* slot_mu   = (const float*)d_in[8];
  const float* slot_sig  = (const float*)d_in[9];
  const float* Wq        = (const float*)d_in[10];
  const float* Wk        = (const float*)d_in[11];
  const float* Wv        = (const float*)d_in[12];
  const float* W_ih      = (const float*)d_in[13];
  const float* W_hh      = (const float*)d_in[14];
  const float* b_ih      = (const float*)d_in[15];
  const float* b_hh      = (const float*)d_in[16];
  const float* W1        = (const float*)d_in[17];
  const float* b1        = (const float*)d_in[18];
  const float* W2        = (const float*)d_in[19];
  const float* b2        = (const float*)d_in[20];

  char* p = (char*)d_ws;
  auto take = [&](size_t bytes) { char* r = p; p += (bytes + 255) & ~(size_t)255; return r; };
  u16* xbf      = (u16*)take((size_t)131072 * 256 * 2);
  u16* kT       = (u16*)take((size_t)32 * 256 * 4096 * 2);
  u16* Vv       = (u16*)take((size_t)32 * 4096 * 256 * 2);
  u16* wkvT     = (u16*)take(131072 * 2);
  u16* wih_f    = (u16*)take(196608 * 2);
  u16* whh_f    = (u16*)take(196608 * 2);
  u16* w1_f     = (u16*)take(131072 * 2);
  u16* w2_f     = (u16*)take(131072 * 2);
  u16* wq_f     = (u16*)take(65536 * 2);
  u16* wqt      = (u16*)take(65536 * 2);
  u16* ufrag    = (u16*)take(65536 * 2);
  u16* hfrag    = (u16*)take(65536 * 2);
  u16* mfrag    = (u16*)take(65536 * 2);
  u16* slfrag   = (u16*)take(65536 * 2);
  u16* h1frag   = (u16*)take(131072 * 2);
  float* snew   = (float*)take(65536 * 4);
  float* slotsA = (float*)take(256 * 256 * 4);
  float* slotsB = (float*)take(256 * 256 * 4);
  float* qbuf   = (float*)take(256 * 256 * 4);
  float* pml    = (float*)take(32 * 16 * 16 * 4);
  float* pupd   = (float*)take((size_t)32 * 16 * 8 * 256 * 4);

  k_convert<<<3584, 256, 0, stream>>>(Wk, Wv, W_ih, W_hh, W1, W2, Wq,
                                      wkvT, wih_f, whh_f, w1_f, w2_f, wq_f, wqt);
  k_ln<<<32768, 256, 0, stream>>>(inputs, ln_in_g, ln_in_b, xbf);
  k_slots_init<<<256, 256, 0, stream>>>(noise, slot_mu, slot_sig, ln_slot_g, ln_slot_b, wqt, slotsA, qbuf);
  k_gemm<<<4096, 256, 0, stream>>>(xbf, wkvT, kT, Vv);

  const float* scur = slotsA;
  for (int it = 0; it < 3; ++it) {
    k_attn<<<512, 128, 0, stream>>>(kT, Vv, qbuf, pml, pupd);
    k_comb<<<64, 256, 0, stream>>>(pml, pupd, scur, ufrag, hfrag);
    k_gru<<<64, 256, 0, stream>>>(ufrag, hfrag, wih_f, whh_f, b_ih, b_hh, scur, snew);
    k_rowln<<<64, 256, 0, stream>>>(snew, ln_mlp_g, ln_mlp_b, mfrag);
    k_mlp1<<<128, 256, 0, stream>>>(mfrag, w1_f, b1, h1frag);
    float* sout = (it == 2) ? (float*)d_out : ((it == 0) ? slotsB : slotsA);
    k_mlp2<<<64, 256, 0, stream>>>(h1frag, w2_f, b2, snew, sout);
    if (it < 2) {
      k_rowln<<<64, 256, 0, stream>>>(sout, ln_slot_g, ln_slot_b, slfrag);
      k_q<<<64, 256, 0, stream>>>(slfrag, wq_f, qbuf);
    }
    scur = sout;
  }
}